// Round 1
// baseline (2997.969 us; speedup 1.0000x reference)
//
#include <hip/hip_runtime.h>

#define EMBED 1024
#define HEADS 16
#define HDIM 64
#define BATCH 4
#define SEQ 2048
#define ROWS (BATCH * SEQ) /* 8192 */

// ---------------------------------------------------------------------------
// fp32 GEMM body: C[m,n] = A[m,:1024] @ W[:1024,n] + bias[n]
// Tile 128x128, BK=8, 256 threads, each thread an 8x8 micro-tile split 4+4
// (cols tx*4 and 64+tx*4; rows ty*4 and 64+ty*4) so LDS float4 reads are
// stride-16B across lanes (conflict-friendly).
// ---------------------------------------------------------------------------
__device__ __forceinline__ void gemm_body(
    const float* __restrict__ A, const float* __restrict__ W,
    const float* __restrict__ bias, float* __restrict__ C)
{
    __shared__ __align__(16) float As[8][128]; // As[k][m] (transposed)
    __shared__ __align__(16) float Bs[8][128]; // Bs[k][n]

    const int tid = threadIdx.x;
    const int m0 = blockIdx.y * 128;
    const int n0 = blockIdx.x * 128;
    const int tx = tid & 15;
    const int ty = tid >> 4;
    const int ar  = tid >> 1;        // 0..127 row in A tile
    const int ak  = (tid & 1) * 4;   // 0 or 4
    const int bkr = tid >> 5;        // 0..7 row in B tile
    const int bc  = (tid & 31) * 4;  // 0..124

    float acc[8][8];
#pragma unroll
    for (int i = 0; i < 8; i++) {
#pragma unroll
        for (int j = 0; j < 8; j++) acc[i][j] = 0.f;
    }

    const float* Ap = A + (size_t)(m0 + ar) * EMBED + ak;
    const float* Wp = W + (size_t)bkr * EMBED + n0 + bc;

    for (int k0 = 0; k0 < EMBED; k0 += 8) {
        float4 av = *(const float4*)(Ap + k0);
        float4 wv = *(const float4*)(Wp + (size_t)k0 * EMBED);
        __syncthreads(); // previous iteration's compute done before overwrite
        As[ak + 0][ar] = av.x;
        As[ak + 1][ar] = av.y;
        As[ak + 2][ar] = av.z;
        As[ak + 3][ar] = av.w;
        *(float4*)&Bs[bkr][bc] = wv;
        __syncthreads();
#pragma unroll
        for (int k = 0; k < 8; k++) {
            float4 a0 = *(const float4*)&As[k][ty * 4];
            float4 a1 = *(const float4*)&As[k][64 + ty * 4];
            float4 b0 = *(const float4*)&Bs[k][tx * 4];
            float4 b1 = *(const float4*)&Bs[k][64 + tx * 4];
            float aa[8] = {a0.x, a0.y, a0.z, a0.w, a1.x, a1.y, a1.z, a1.w};
            float bb[8] = {b0.x, b0.y, b0.z, b0.w, b1.x, b1.y, b1.z, b1.w};
#pragma unroll
            for (int i = 0; i < 8; i++) {
#pragma unroll
                for (int j = 0; j < 8; j++)
                    acc[i][j] = fmaf(aa[i], bb[j], acc[i][j]);
            }
        }
    }

    float4 bi0 = *(const float4*)&bias[n0 + tx * 4];
    float4 bi1 = *(const float4*)&bias[n0 + 64 + tx * 4];
    float bcol[8] = {bi0.x, bi0.y, bi0.z, bi0.w, bi1.x, bi1.y, bi1.z, bi1.w};
#pragma unroll
    for (int i = 0; i < 8; i++) {
        int row = m0 + ((i < 4) ? (ty * 4 + i) : (64 + ty * 4 + (i - 4)));
        float4 o0 = {acc[i][0] + bcol[0], acc[i][1] + bcol[1],
                     acc[i][2] + bcol[2], acc[i][3] + bcol[3]};
        float4 o1 = {acc[i][4] + bcol[4], acc[i][5] + bcol[5],
                     acc[i][6] + bcol[6], acc[i][7] + bcol[7]};
        *(float4*)&C[(size_t)row * EMBED + n0 + tx * 4] = o0;
        *(float4*)&C[(size_t)row * EMBED + n0 + 64 + tx * 4] = o1;
    }
}

__global__ __launch_bounds__(256) void gemm_kernel(
    const float* __restrict__ A, const float* __restrict__ W,
    const float* __restrict__ bias, float* __restrict__ C)
{
    gemm_body(A, W, bias, C);
}

// Fused Q/K/V projection: blockIdx.z selects which weight/bias/output.
__global__ __launch_bounds__(256) void qkv_kernel(
    const float* __restrict__ X,
    const float* __restrict__ Wq, const float* __restrict__ bq, float* Qb,
    const float* __restrict__ Wk, const float* __restrict__ bk, float* Kb,
    const float* __restrict__ Wv, const float* __restrict__ bv, float* Vb)
{
    const float* W; const float* bias; float* C;
    if (blockIdx.z == 0)      { W = Wq; bias = bq; C = Qb; }
    else if (blockIdx.z == 1) { W = Wk; bias = bk; C = Kb; }
    else                      { W = Wv; bias = bv; C = Vb; }
    gemm_body(X, W, bias, C);
}

// ---------------------------------------------------------------------------
// Flash-style attention, fp32. One thread per q-row; grid (SEQ/256, H, B).
// q (64) and O-accumulator (64) live in registers; K/V 64x64 tiles in LDS.
// Online softmax with one rescale per 16-k subtile. Masked -> -1e30 (an
// all-masked row degenerates to uniform attention, matching the reference).
// Out may alias Q (this block's Q region is fully consumed before the write).
// ---------------------------------------------------------------------------
__global__ __launch_bounds__(256) void attn_kernel(
    const float* Q, const float* __restrict__ Kg,
    const float* __restrict__ Vg, const int* __restrict__ mask,
    float* Out)
{
    __shared__ __align__(16) float Ks[64][68]; // +4 pad: store conflicts
    __shared__ __align__(16) float Vs[64][68];

    const int tid = threadIdx.x;
    const int b = blockIdx.z;
    const int h = blockIdx.y;
    const int q = blockIdx.x * 256 + tid;

    float qreg[64];
    {
        const float* qp = Q + (size_t)(b * SEQ + q) * EMBED + h * HDIM;
#pragma unroll
        for (int d = 0; d < 64; d += 4) {
            float4 t = *(const float4*)(qp + d);
            qreg[d]     = t.x * 0.125f; // fold 1/sqrt(64) into q
            qreg[d + 1] = t.y * 0.125f;
            qreg[d + 2] = t.z * 0.125f;
            qreg[d + 3] = t.w * 0.125f;
        }
    }
    float o[64];
#pragma unroll
    for (int d = 0; d < 64; d++) o[d] = 0.f;
    float mrow = -3.0e38f, lrow = 0.f;

    const int* mp = mask + ((size_t)b * SEQ + q) * SEQ;
    const size_t kvbase = (size_t)b * SEQ * EMBED + (size_t)h * HDIM;
    const int lr = tid >> 2;       // 0..63 : K/V tile row this thread stages
    const int lc = (tid & 3) * 4;  // 0/4/8/12

#pragma unroll 1
    for (int kt = 0; kt < SEQ; kt += 64) {
        __syncthreads(); // previous tile fully consumed
        {
            const float* kp = Kg + kvbase + (size_t)(kt + lr) * EMBED;
            const float* vp = Vg + kvbase + (size_t)(kt + lr) * EMBED;
#pragma unroll
            for (int c = lc; c < 64; c += 16) {
                *(float4*)&Ks[lr][c] = *(const float4*)(kp + c);
                *(float4*)&Vs[lr][c] = *(const float4*)(vp + c);
            }
        }
        __syncthreads();

#pragma unroll 1
        for (int st = 0; st < 64; st += 16) {
            // mask bits for this subtile (contiguous in k per thread)
            int mk[16];
#pragma unroll
            for (int j = 0; j < 4; j++) {
                int4 t = *(const int4*)(mp + kt + st + j * 4);
                mk[j * 4 + 0] = t.x; mk[j * 4 + 1] = t.y;
                mk[j * 4 + 2] = t.z; mk[j * 4 + 3] = t.w;
            }
            // scores
            float s[16];
#pragma unroll
            for (int i = 0; i < 16; i++) {
                float a0 = 0.f, a1 = 0.f, a2 = 0.f, a3 = 0.f;
#pragma unroll
                for (int d = 0; d < 64; d += 4) {
                    float4 kv = *(const float4*)&Ks[st + i][d];
                    a0 = fmaf(qreg[d],     kv.x, a0);
                    a1 = fmaf(qreg[d + 1], kv.y, a1);
                    a2 = fmaf(qreg[d + 2], kv.z, a2);
                    a3 = fmaf(qreg[d + 3], kv.w, a3);
                }
                float sv = (a0 + a1) + (a2 + a3);
                s[i] = (mk[i] != 0) ? sv : -1.0e30f;
            }
            // online softmax update (one rescale per subtile)
            float tmax = s[0];
#pragma unroll
            for (int i = 1; i < 16; i++) tmax = fmaxf(tmax, s[i]);
            float mnew  = fmaxf(mrow, tmax);
            float alpha = __expf(mrow - mnew);
            float psum  = 0.f;
#pragma unroll
            for (int i = 0; i < 16; i++) {
                s[i] = __expf(s[i] - mnew);
                psum += s[i];
            }
            lrow = lrow * alpha + psum;
            mrow = mnew;
#pragma unroll
            for (int d = 0; d < 64; d++) o[d] *= alpha;
            // O += P @ V
#pragma unroll
            for (int i = 0; i < 16; i++) {
                float p = s[i];
#pragma unroll
                for (int d = 0; d < 64; d += 4) {
                    float4 vv = *(const float4*)&Vs[st + i][d];
                    o[d]     = fmaf(p, vv.x, o[d]);
                    o[d + 1] = fmaf(p, vv.y, o[d + 1]);
                    o[d + 2] = fmaf(p, vv.z, o[d + 2]);
                    o[d + 3] = fmaf(p, vv.w, o[d + 3]);
                }
            }
        }
    }

    float inv = 1.0f / lrow;
    float* op = Out + (size_t)(b * SEQ + q) * EMBED + h * HDIM;
#pragma unroll
    for (int d = 0; d < 64; d += 4) {
        float4 ov = {o[d] * inv, o[d + 1] * inv, o[d + 2] * inv, o[d + 3] * inv};
        *(float4*)&op[d] = ov;
    }
}

extern "C" void kernel_launch(void* const* d_in, const int* in_sizes, int n_in,
                              void* d_out, int out_size, void* d_ws, size_t ws_size,
                              hipStream_t stream)
{
    const float* x    = (const float*)d_in[0];
    const int*   mask = (const int*)d_in[1];
    const float* Wq   = (const float*)d_in[2];
    const float* bq   = (const float*)d_in[3];
    const float* Wk   = (const float*)d_in[4];
    const float* bk   = (const float*)d_in[5];
    const float* Wv   = (const float*)d_in[6];
    const float* bv   = (const float*)d_in[7];
    const float* Wo   = (const float*)d_in[8];
    const float* bo   = (const float*)d_in[9];
    float* outp = (float*)d_out;

    const size_t MAT = (size_t)ROWS * EMBED; // 8.4M floats = 32 MiB
    float* Qb = (float*)d_ws;
    float* Kb = Qb + MAT;
    float* Vb = Kb + MAT;
    // attention output is written in-place over Qb (safe: each block reads its
    // own Q region into registers before writing the same region).

    dim3 gqkv(EMBED / 128, ROWS / 128, 3);
    qkv_kernel<<<gqkv, 256, 0, stream>>>(x, Wq, bq, Qb, Wk, bk, Kb, Wv, bv, Vb);

    dim3 gattn(SEQ / 256, HEADS, BATCH);
    attn_kernel<<<gattn, 256, 0, stream>>>(Qb, Kb, Vb, mask, Qb);

    dim3 gout(EMBED / 128, ROWS / 128);
    gemm_kernel<<<gout, 256, 0, stream>>>(Qb, Wo, bo, outp);
}

// Round 2
// 489.340 us; speedup vs baseline: 6.1266x; 6.1266x over previous
//
#include <hip/hip_runtime.h>

#define EMBED 1024
#define HEADS 16
#define HDIM 64
#define BATCH 4
#define SEQ 2048
#define ROWS (BATCH * SEQ) /* 8192 */

typedef __attribute__((ext_vector_type(8))) short bf16x8;  // 8 bf16 = 4 VGPRs
typedef __attribute__((ext_vector_type(4))) float f32x4;   // MFMA 16x16 acc

#define MFMA16(a, b, c) __builtin_amdgcn_mfma_f32_16x16x32_bf16(a, b, c, 0, 0, 0)

__device__ __forceinline__ unsigned short f2bf(float f) {
    union { float f; unsigned int u; } x; x.f = f;
    unsigned int r = x.u + 0x7fffu + ((x.u >> 16) & 1u); // RNE
    return (unsigned short)(r >> 16);
}

// ---------------------------------------------------------------------------
// Prep: x fp32 -> bf16
// ---------------------------------------------------------------------------
__global__ __launch_bounds__(256) void cvt_x_kernel(
    const float* __restrict__ in, unsigned short* __restrict__ out)
{
    int i = (blockIdx.x * 256 + threadIdx.x) * 4;
    float4 v = *(const float4*)(in + i);
    ushort4 o;
    o.x = f2bf(v.x); o.y = f2bf(v.y); o.z = f2bf(v.z); o.w = f2bf(v.w);
    *(ushort4*)(out + i) = o;
}

// Prep: W (K x N, row-major fp32) -> Wt (N x K, row-major bf16), 4 matrices.
__global__ __launch_bounds__(256) void wtrans_kernel(
    const float* __restrict__ W0, const float* __restrict__ W1,
    const float* __restrict__ W2, const float* __restrict__ W3,
    unsigned short* __restrict__ Wt)
{
    __shared__ float t[32][33];
    const float* W = (blockIdx.z == 0) ? W0 : (blockIdx.z == 1) ? W1
                   : (blockIdx.z == 2) ? W2 : W3;
    unsigned short* o = Wt + (size_t)blockIdx.z * EMBED * EMBED;
    int tx = threadIdx.x & 31, ty = threadIdx.x >> 5;
    int bx = blockIdx.x * 32, by = blockIdx.y * 32; // bx: n, by: k
#pragma unroll
    for (int r = 0; r < 32; r += 8)
        t[ty + r][tx] = W[(size_t)(by + ty + r) * EMBED + bx + tx];
    __syncthreads();
#pragma unroll
    for (int r = 0; r < 32; r += 8)
        o[(size_t)(bx + ty + r) * EMBED + by + tx] = f2bf(t[tx][ty + r]);
}

// Prep: mask int32 -> u8 (0/1)
__global__ __launch_bounds__(256) void cvt_mask_kernel(
    const int* __restrict__ in, unsigned char* __restrict__ out)
{
    int i = (blockIdx.x * 256 + threadIdx.x) * 4;
    int4 v = *(const int4*)(in + i);
    uchar4 o;
    o.x = v.x != 0; o.y = v.y != 0; o.z = v.z != 0; o.w = v.w != 0;
    *(uchar4*)(out + i) = o;
}

// V (row-major [b*SEQ+k][h*64+d] bf16) -> Vt [b][h][d][k] bf16
__global__ __launch_bounds__(256) void vtrans_kernel(
    const unsigned short* __restrict__ Vb, unsigned short* __restrict__ Vt)
{
    __shared__ unsigned short t[64][72];
    int b = blockIdx.z, h = blockIdx.y, k0 = blockIdx.x * 64;
    int r = threadIdx.x >> 2, c = (threadIdx.x & 3) * 16;
    const unsigned short* src = Vb + (size_t)(b * SEQ + k0 + r) * EMBED + h * HDIM + c;
    *(uint4*)&t[r][c]     = *(const uint4*)(src);
    *(uint4*)&t[r][c + 8] = *(const uint4*)(src + 8);
    __syncthreads();
    unsigned short* dst = Vt + (size_t)((b * HEADS + h) * HDIM + r) * SEQ + k0 + c;
    union { unsigned short u[8]; uint4 v; } p0, p1;
#pragma unroll
    for (int i = 0; i < 8; i++) p0.u[i] = t[c + i][r];
#pragma unroll
    for (int i = 0; i < 8; i++) p1.u[i] = t[c + 8 + i][r];
    *(uint4*)dst       = p0.v;
    *(uint4*)(dst + 8) = p1.v;
}

// ---------------------------------------------------------------------------
// bf16 MFMA GEMM: C[m][n] = A[m][k] @ Bt[n][k]^T + bias[n]
// 128x128 tile, BK=32, 256 thr = 4 waves (2x2), 4x4 16x16x32 tiles per wave.
// A-frag: m=lane&15, k=(lane>>4)*8+j ; B-frag: n=lane&15, same k (m89 layout).
// C/D: row=(lane>>4)*4+reg, col=lane&15.
// ---------------------------------------------------------------------------
__device__ __forceinline__ void gemm_bf16_body(
    const unsigned short* __restrict__ A, const unsigned short* __restrict__ Bt,
    const float* __restrict__ bias,
    float* __restrict__ outF, unsigned short* __restrict__ outB, float scale)
{
    __shared__ unsigned short As[128][40]; // +8 pad: 80 B stride, 16B-aligned, 2-way banks
    __shared__ unsigned short Bs[128][40];
    const int tid = threadIdx.x;
    const int lane = tid & 63, wid = tid >> 6;
    const int ln = lane & 15, lg = lane >> 4;
    const int wy = wid >> 1, wx = wid & 1;
    const int m0 = blockIdx.y * 128, n0 = blockIdx.x * 128;
    const int sr = tid >> 1, sc = (tid & 1) * 16;
    const unsigned short* Ap = A + (size_t)(m0 + sr) * EMBED + sc;
    const unsigned short* Bp = Bt + (size_t)(n0 + sr) * EMBED + sc;

    f32x4 acc[4][4];
#pragma unroll
    for (int i = 0; i < 4; i++)
#pragma unroll
        for (int j = 0; j < 4; j++) acc[i][j] = (f32x4){0.f, 0.f, 0.f, 0.f};

    for (int k0 = 0; k0 < EMBED; k0 += 32) {
        uint4 a0 = *(const uint4*)(Ap + k0);
        uint4 a1 = *(const uint4*)(Ap + k0 + 8);
        uint4 b0 = *(const uint4*)(Bp + k0);
        uint4 b1 = *(const uint4*)(Bp + k0 + 8);
        __syncthreads();
        *(uint4*)&As[sr][sc] = a0; *(uint4*)&As[sr][sc + 8] = a1;
        *(uint4*)&Bs[sr][sc] = b0; *(uint4*)&Bs[sr][sc + 8] = b1;
        __syncthreads();
        bf16x8 af[4], bfr[4];
#pragma unroll
        for (int mi = 0; mi < 4; mi++)
            af[mi] = *(const bf16x8*)&As[wy * 64 + mi * 16 + ln][lg * 8];
#pragma unroll
        for (int nj = 0; nj < 4; nj++)
            bfr[nj] = *(const bf16x8*)&Bs[wx * 64 + nj * 16 + ln][lg * 8];
#pragma unroll
        for (int mi = 0; mi < 4; mi++)
#pragma unroll
            for (int nj = 0; nj < 4; nj++)
                acc[mi][nj] = MFMA16(af[mi], bfr[nj], acc[mi][nj]);
    }

#pragma unroll
    for (int mi = 0; mi < 4; mi++) {
#pragma unroll
        for (int nj = 0; nj < 4; nj++) {
            int row = m0 + wy * 64 + mi * 16 + lg * 4;
            int col = n0 + wx * 64 + nj * 16 + ln;
            float bv = bias[col];
#pragma unroll
            for (int r = 0; r < 4; r++) {
                float v = (acc[mi][nj][r] + bv) * scale;
                if (outF) outF[(size_t)(row + r) * EMBED + col] = v;
                else      outB[(size_t)(row + r) * EMBED + col] = f2bf(v);
            }
        }
    }
}

__global__ __launch_bounds__(256) void qkv_gemm_kernel(
    const unsigned short* __restrict__ Xb, const unsigned short* __restrict__ Wt,
    const float* __restrict__ bq, const float* __restrict__ bk,
    const float* __restrict__ bv,
    unsigned short* __restrict__ Qb, unsigned short* __restrict__ Kb,
    unsigned short* __restrict__ Vb)
{
    int z = blockIdx.z;
    const unsigned short* Bt = Wt + (size_t)z * EMBED * EMBED;
    const float* bias = (z == 0) ? bq : (z == 1) ? bk : bv;
    unsigned short* out = (z == 0) ? Qb : (z == 1) ? Kb : Vb;
    float scale = (z == 0) ? 0.125f : 1.0f; // fold 1/sqrt(HDIM) into Q
    gemm_bf16_body(Xb, Bt, bias, nullptr, out, scale);
}

__global__ __launch_bounds__(256) void out_gemm_kernel(
    const unsigned short* __restrict__ Ob, const unsigned short* __restrict__ Wto,
    const float* __restrict__ bo, float* __restrict__ out)
{
    gemm_bf16_body(Ob, Wto, bo, out, nullptr, 1.0f);
}

// ---------------------------------------------------------------------------
// Flash attention, bf16 MFMA. Block = 128 q rows (4 waves x 32), k-tiles of 64.
// S^T = K·Q^T per tile (C/D layout then has 4 consecutive k per lane: uchar4
// mask loads, 2-step shfl row-reduce, packed b64 P writes). P and V read back
// as A/B fragments (Ps[q][k], Vs[d][k] both k-contiguous). O in C-layout.
// ---------------------------------------------------------------------------
__global__ __launch_bounds__(256) void attn_mfma_kernel(
    const unsigned short* __restrict__ Qb, const unsigned short* __restrict__ Kb,
    const unsigned short* __restrict__ Vt, const unsigned char* __restrict__ mask8,
    unsigned short* __restrict__ Ob)
{
    __shared__ unsigned short Ks[64][72];      // [kseq][d]
    __shared__ unsigned short Vs[64][72];      // [d][kseq]
    __shared__ unsigned short Ps[4][32][72];   // per-wave [q][kseq]
    const int tid = threadIdx.x;
    const int lane = tid & 63, wid = tid >> 6;
    const int ln = lane & 15, lg = lane >> 4;
    const int b = blockIdx.z, h = blockIdx.y;
    const int q0 = blockIdx.x * 128 + wid * 32;

    bf16x8 qf[2][2]; // [mi][ks] A/B-frag layout: row q0+mi*16+ln, d = ks*32+lg*8..
#pragma unroll
    for (int mi = 0; mi < 2; mi++)
#pragma unroll
        for (int ks = 0; ks < 2; ks++)
            qf[mi][ks] = *(const bf16x8*)(Qb +
                (size_t)(b * SEQ + q0 + mi * 16 + ln) * EMBED + h * HDIM + ks * 32 + lg * 8);

    f32x4 o[2][4];
#pragma unroll
    for (int mi = 0; mi < 2; mi++)
#pragma unroll
        for (int dj = 0; dj < 4; dj++) o[mi][dj] = (f32x4){0.f, 0.f, 0.f, 0.f};
    float mr[2] = {-3.0e38f, -3.0e38f}; // stats for q = mi*16+ln
    float lr[2] = {0.f, 0.f};

    const unsigned char* mp = mask8 + (size_t)b * SEQ * SEQ;
    const int kr = tid >> 2, kc = (tid & 3) * 16;

    for (int kt = 0; kt < SEQ; kt += 64) {
        __syncthreads();
        {
            const unsigned short* s = Kb + (size_t)(b * SEQ + kt + kr) * EMBED + h * HDIM + kc;
            *(uint4*)&Ks[kr][kc]     = *(const uint4*)(s);
            *(uint4*)&Ks[kr][kc + 8] = *(const uint4*)(s + 8);
            const unsigned short* v = Vt + (size_t)((b * HEADS + h) * HDIM + kr) * SEQ + kt + kc;
            *(uint4*)&Vs[kr][kc]     = *(const uint4*)(v);
            *(uint4*)&Vs[kr][kc + 8] = *(const uint4*)(v + 8);
        }
        __syncthreads();

        // S^T tiles: rows = kseq (nj*16 + lg*4 + reg), cols = q (mi*16 + ln)
        f32x4 S[2][4];
#pragma unroll
        for (int nj = 0; nj < 4; nj++) {
            bf16x8 k0 = *(const bf16x8*)&Ks[nj * 16 + ln][lg * 8];
            bf16x8 k1 = *(const bf16x8*)&Ks[nj * 16 + ln][32 + lg * 8];
#pragma unroll
            for (int mi = 0; mi < 2; mi++) {
                f32x4 t = (f32x4){0.f, 0.f, 0.f, 0.f};
                t = MFMA16(k0, qf[mi][0], t);
                t = MFMA16(k1, qf[mi][1], t);
                S[mi][nj] = t;
            }
        }

#pragma unroll
        for (int mi = 0; mi < 2; mi++) {
            const unsigned char* mq = mp + (size_t)(q0 + mi * 16 + ln) * SEQ + kt;
#pragma unroll
            for (int nj = 0; nj < 4; nj++) {
                uchar4 mv = *(const uchar4*)(mq + nj * 16 + lg * 4);
                S[mi][nj][0] = mv.x ? S[mi][nj][0] : -1.0e30f;
                S[mi][nj][1] = mv.y ? S[mi][nj][1] : -1.0e30f;
                S[mi][nj][2] = mv.z ? S[mi][nj][2] : -1.0e30f;
                S[mi][nj][3] = mv.w ? S[mi][nj][3] : -1.0e30f;
            }
            // row max over this tile (16 candidates/lane, x4 lane groups)
            float mx = S[mi][0][0];
#pragma unroll
            for (int nj = 0; nj < 4; nj++)
                mx = fmaxf(mx, fmaxf(fmaxf(S[mi][nj][0], S[mi][nj][1]),
                                     fmaxf(S[mi][nj][2], S[mi][nj][3])));
            mx = fmaxf(mx, __shfl_xor(mx, 16));
            mx = fmaxf(mx, __shfl_xor(mx, 32));
            float mnew = fmaxf(mr[mi], mx);
            float al = __expf(mr[mi] - mnew);
            mr[mi] = mnew;
            float rs = 0.f;
#pragma unroll
            for (int nj = 0; nj < 4; nj++)
#pragma unroll
                for (int r = 0; r < 4; r++) {
                    float p = __expf(S[mi][nj][r] - mnew);
                    S[mi][nj][r] = p;
                    rs += p;
                }
            rs += __shfl_xor(rs, 16);
            rs += __shfl_xor(rs, 32);
            lr[mi] = lr[mi] * al + rs;
            // O rows are lg*4+reg -> fetch alpha from lane (lg*4+reg)
            float al0 = __shfl(al, lg * 4 + 0);
            float al1 = __shfl(al, lg * 4 + 1);
            float al2 = __shfl(al, lg * 4 + 2);
            float al3 = __shfl(al, lg * 4 + 3);
#pragma unroll
            for (int dj = 0; dj < 4; dj++) {
                o[mi][dj][0] *= al0; o[mi][dj][1] *= al1;
                o[mi][dj][2] *= al2; o[mi][dj][3] *= al3;
            }
            // P write: 4 consecutive kseq per lane -> packed 8 B
#pragma unroll
            for (int nj = 0; nj < 4; nj++) {
                ushort4 pw;
                pw.x = f2bf(S[mi][nj][0]); pw.y = f2bf(S[mi][nj][1]);
                pw.z = f2bf(S[mi][nj][2]); pw.w = f2bf(S[mi][nj][3]);
                *(ushort4*)&Ps[wid][mi * 16 + ln][nj * 16 + lg * 4] = pw;
            }
        }

        // O += P @ V  (A from Ps[q][k], B from Vs[d][k], both k-contiguous)
#pragma unroll
        for (int ks = 0; ks < 2; ks++) {
            bf16x8 p0 = *(const bf16x8*)&Ps[wid][ln][ks * 32 + lg * 8];
            bf16x8 p1 = *(const bf16x8*)&Ps[wid][16 + ln][ks * 32 + lg * 8];
#pragma unroll
            for (int dj = 0; dj < 4; dj++) {
                bf16x8 vf = *(const bf16x8*)&Vs[dj * 16 + ln][ks * 32 + lg * 8];
                o[0][dj] = MFMA16(p0, vf, o[0][dj]);
                o[1][dj] = MFMA16(p1, vf, o[1][dj]);
            }
        }
    }

#pragma unroll
    for (int mi = 0; mi < 2; mi++) {
        float li = 1.0f / lr[mi];
        float l0 = __shfl(li, lg * 4 + 0);
        float l1 = __shfl(li, lg * 4 + 1);
        float l2 = __shfl(li, lg * 4 + 2);
        float l3 = __shfl(li, lg * 4 + 3);
#pragma unroll
        for (int dj = 0; dj < 4; dj++) {
            unsigned short* op = Ob + (size_t)(b * SEQ + q0 + mi * 16 + lg * 4) * EMBED
                                    + h * HDIM + dj * 16 + ln;
            op[0]         = f2bf(o[mi][dj][0] * l0);
            op[EMBED]     = f2bf(o[mi][dj][1] * l1);
            op[2 * EMBED] = f2bf(o[mi][dj][2] * l2);
            op[3 * EMBED] = f2bf(o[mi][dj][3] * l3);
        }
    }
}

extern "C" void kernel_launch(void* const* d_in, const int* in_sizes, int n_in,
                              void* d_out, int out_size, void* d_ws, size_t ws_size,
                              hipStream_t stream)
{
    const float* x  = (const float*)d_in[0];
    const int* mask = (const int*)d_in[1];
    const float* Wq = (const float*)d_in[2];
    const float* bq = (const float*)d_in[3];
    const float* Wk = (const float*)d_in[4];
    const float* bk = (const float*)d_in[5];
    const float* Wv = (const float*)d_in[6];
    const float* bv = (const float*)d_in[7];
    const float* Wo = (const float*)d_in[8];
    const float* bo = (const float*)d_in[9];
    float* outp = (float*)d_out;

    // Workspace layout (88 MB total; round-1 used 96 MB OK):
    //   [0,8)   Wt: 4x bf16 1024x1024 (transposed weights)
    //   [8,24)  mask8
    //   [24,40) Xb (bf16 x) -- aliased by Vt after QKV GEMM consumes Xb
    //   [40,56) Qb  [56,72) Kb  [72,88) Vb -- Vb aliased by Ob after vtrans
    char* ws = (char*)d_ws;
    unsigned short* Wt = (unsigned short*)(ws);
    unsigned char*  m8 = (unsigned char*)(ws + ((size_t)8 << 20));
    unsigned short* Xb = (unsigned short*)(ws + ((size_t)24 << 20));
    unsigned short* Vt = Xb;
    unsigned short* Qb = (unsigned short*)(ws + ((size_t)40 << 20));
    unsigned short* Kb = (unsigned short*)(ws + ((size_t)56 << 20));
    unsigned short* Vb = (unsigned short*)(ws + ((size_t)72 << 20));
    unsigned short* Ob = Vb;

    cvt_x_kernel<<<ROWS * EMBED / 1024, 256, 0, stream>>>(x, Xb);
    wtrans_kernel<<<dim3(32, 32, 4), 256, 0, stream>>>(Wq, Wk, Wv, Wo, Wt);
    cvt_mask_kernel<<<(size_t)BATCH * SEQ * SEQ / 1024, 256, 0, stream>>>(mask, m8);
    qkv_gemm_kernel<<<dim3(EMBED / 128, ROWS / 128, 3), 256, 0, stream>>>(
        Xb, Wt, bq, bk, bv, Qb, Kb, Vb);
    vtrans_kernel<<<dim3(SEQ / 64, HEADS, BATCH), 256, 0, stream>>>(Vb, Vt);
    attn_mfma_kernel<<<dim3(SEQ / 128, HEADS, BATCH), 256, 0, stream>>>(
        Qb, Kb, Vt, m8, Ob);
    out_gemm_kernel<<<dim3(EMBED / 128, ROWS / 128), 256, 0, stream>>>(
        Ob, Wt + (size_t)3 * EMBED * EMBED, bo, outp);
}

// Round 3
// 429.050 us; speedup vs baseline: 6.9875x; 1.1405x over previous
//
#include <hip/hip_runtime.h>
#include <hip/hip_bf16.h>

#define EMBED 1024
#define HEADS 16
#define HDIM 64
#define BATCH 4
#define SEQ 2048
#define ROWS (BATCH * SEQ) /* 8192 */
#define LOG2E 1.4426950408889634f

typedef __attribute__((ext_vector_type(8))) short bf16x8;  // 8 bf16 = 4 VGPRs
typedef __attribute__((ext_vector_type(4))) float f32x4;   // MFMA 16x16 acc

#define MFMA16(a, b, c) __builtin_amdgcn_mfma_f32_16x16x32_bf16(a, b, c, 0, 0, 0)

__device__ __forceinline__ unsigned short f2bf(float f) {
    union { float f; unsigned int u; } x; x.f = f;
    unsigned int r = x.u + 0x7fffu + ((x.u >> 16) & 1u); // RNE
    return (unsigned short)(r >> 16);
}

__device__ __forceinline__ ushort2 pk2(float a, float b) {
    union { __hip_bfloat162 h; ushort2 u; } c;
    c.h = __float22bfloat162_rn(make_float2(a, b)); // packed v_cvt_pk_bf16_f32
    return c.u;
}

// async global->LDS, 16 B per lane; lds dest = wave-uniform base + lane*16
__device__ __forceinline__ void gl2lds(const unsigned short* g, unsigned short* l) {
    __builtin_amdgcn_global_load_lds(
        (const __attribute__((address_space(1))) unsigned int*)g,
        (__attribute__((address_space(3))) unsigned int*)l, 16, 0, 0);
}

// ---------------------------------------------------------------------------
// Prep kernels
// ---------------------------------------------------------------------------
__global__ __launch_bounds__(256) void cvt_x_kernel(
    const float* __restrict__ in, unsigned short* __restrict__ out)
{
    int i = (blockIdx.x * 256 + threadIdx.x) * 4;
    float4 v = *(const float4*)(in + i);
    ushort2 a = pk2(v.x, v.y), b = pk2(v.z, v.w);
    ushort4 o; o.x = a.x; o.y = a.y; o.z = b.x; o.w = b.y;
    *(ushort4*)(out + i) = o;
}

// W (K x N, row-major fp32) -> Wt (N x K, row-major bf16), 4 matrices.
__global__ __launch_bounds__(256) void wtrans_kernel(
    const float* __restrict__ W0, const float* __restrict__ W1,
    const float* __restrict__ W2, const float* __restrict__ W3,
    unsigned short* __restrict__ Wt)
{
    __shared__ float t[32][33];
    const float* W = (blockIdx.z == 0) ? W0 : (blockIdx.z == 1) ? W1
                   : (blockIdx.z == 2) ? W2 : W3;
    unsigned short* o = Wt + (size_t)blockIdx.z * EMBED * EMBED;
    int tx = threadIdx.x & 31, ty = threadIdx.x >> 5;
    int bx = blockIdx.x * 32, by = blockIdx.y * 32;
#pragma unroll
    for (int r = 0; r < 32; r += 8)
        t[ty + r][tx] = W[(size_t)(by + ty + r) * EMBED + bx + tx];
    __syncthreads();
#pragma unroll
    for (int r = 0; r < 32; r += 8)
        o[(size_t)(bx + ty + r) * EMBED + by + tx] = f2bf(t[tx][ty + r]);
}

__global__ __launch_bounds__(256) void cvt_mask_kernel(
    const int* __restrict__ in, unsigned char* __restrict__ out)
{
    int i = (blockIdx.x * 256 + threadIdx.x) * 4;
    int4 v = *(const int4*)(in + i);
    uchar4 o;
    o.x = v.x != 0; o.y = v.y != 0; o.z = v.z != 0; o.w = v.w != 0;
    *(uchar4*)(out + i) = o;
}

// V (row-major [b*SEQ+k][h*64+d] bf16) -> Vt [b][h][d][k] bf16
__global__ __launch_bounds__(256) void vtrans_kernel(
    const unsigned short* __restrict__ Vb, unsigned short* __restrict__ Vt)
{
    __shared__ unsigned short t[64][72];
    int b = blockIdx.z, h = blockIdx.y, k0 = blockIdx.x * 64;
    int r = threadIdx.x >> 2, c = (threadIdx.x & 3) * 16;
    const unsigned short* src = Vb + (size_t)(b * SEQ + k0 + r) * EMBED + h * HDIM + c;
    *(uint4*)&t[r][c]     = *(const uint4*)(src);
    *(uint4*)&t[r][c + 8] = *(const uint4*)(src + 8);
    __syncthreads();
    unsigned short* dst = Vt + (size_t)((b * HEADS + h) * HDIM + r) * SEQ + k0 + c;
    union { unsigned short u[8]; uint4 v; } p0, p1;
#pragma unroll
    for (int i = 0; i < 8; i++) p0.u[i] = t[c + i][r];
#pragma unroll
    for (int i = 0; i < 8; i++) p1.u[i] = t[c + 8 + i][r];
    *(uint4*)dst       = p0.v;
    *(uint4*)(dst + 8) = p1.v;
}

// ---------------------------------------------------------------------------
// bf16 MFMA GEMM, m97-style: 128x128 tile, BK=32, unpadded LDS, staged with
// global_load_lds width=16 (4 instrs/thread/k-step). 4 waves, 4x4 16x16x32.
// ---------------------------------------------------------------------------
__device__ __forceinline__ void gemm_bf16_body(
    const unsigned short* __restrict__ A, const unsigned short* __restrict__ Bt,
    const float* __restrict__ bias,
    float* __restrict__ outF, unsigned short* __restrict__ outB, float scale)
{
    __shared__ unsigned short As[128][32]; // 8 KB, row = 64 B (lane-order for DMA)
    __shared__ unsigned short Bs[128][32];
    const int tid = threadIdx.x;
    const int lane = tid & 63, wid = tid >> 6;
    const int ln = lane & 15, lg = lane >> 4;
    const int wy = wid >> 1, wx = wid & 1;
    const int m0 = blockIdx.y * 128, n0 = blockIdx.x * 128;
    const int srow = tid >> 2;          // 0..63
    const int scol = (tid & 3) * 8;     // 16 B chunks of a 64 B row
    const unsigned short* Ap = A + (size_t)(m0 + srow) * EMBED + scol;
    const unsigned short* Bp = Bt + (size_t)(n0 + srow) * EMBED + scol;
    unsigned short* lA = &As[srow & ~15][0]; // wave-uniform: &As[16*wid][0]
    unsigned short* lB = &Bs[srow & ~15][0];

    f32x4 acc[4][4];
#pragma unroll
    for (int i = 0; i < 4; i++)
#pragma unroll
        for (int j = 0; j < 4; j++) acc[i][j] = (f32x4){0.f, 0.f, 0.f, 0.f};

    for (int k0 = 0; k0 < EMBED; k0 += 32) {
        __syncthreads(); // prior tile's LDS reads complete
        gl2lds(Ap + k0, lA);
        gl2lds(Ap + (size_t)64 * EMBED + k0, lA + 64 * 32);
        gl2lds(Bp + k0, lB);
        gl2lds(Bp + (size_t)64 * EMBED + k0, lB + 64 * 32);
        __syncthreads(); // DMA drained (vmcnt 0 before barrier)
        bf16x8 af[4], bfr[4];
#pragma unroll
        for (int mi = 0; mi < 4; mi++)
            af[mi] = *(const bf16x8*)&As[wy * 64 + mi * 16 + ln][lg * 8];
#pragma unroll
        for (int nj = 0; nj < 4; nj++)
            bfr[nj] = *(const bf16x8*)&Bs[wx * 64 + nj * 16 + ln][lg * 8];
#pragma unroll
        for (int mi = 0; mi < 4; mi++)
#pragma unroll
            for (int nj = 0; nj < 4; nj++)
                acc[mi][nj] = MFMA16(af[mi], bfr[nj], acc[mi][nj]);
    }

#pragma unroll
    for (int mi = 0; mi < 4; mi++) {
#pragma unroll
        for (int nj = 0; nj < 4; nj++) {
            int row = m0 + wy * 64 + mi * 16 + lg * 4;
            int col = n0 + wx * 64 + nj * 16 + ln;
            float bv = bias[col];
#pragma unroll
            for (int r = 0; r < 4; r++) {
                float v = (acc[mi][nj][r] + bv) * scale;
                if (outF) outF[(size_t)(row + r) * EMBED + col] = v;
                else      outB[(size_t)(row + r) * EMBED + col] = f2bf(v);
            }
        }
    }
}

__global__ __launch_bounds__(256) void qkv_gemm_kernel(
    const unsigned short* __restrict__ Xb, const unsigned short* __restrict__ Wt,
    const float* __restrict__ bq, const float* __restrict__ bk,
    const float* __restrict__ bv,
    unsigned short* __restrict__ Qb, unsigned short* __restrict__ Kb,
    unsigned short* __restrict__ Vb)
{
    int z = blockIdx.z;
    const unsigned short* Bt = Wt + (size_t)z * EMBED * EMBED;
    const float* bias = (z == 0) ? bq : (z == 1) ? bk : bv;
    unsigned short* out = (z == 0) ? Qb : (z == 1) ? Kb : Vb;
    // fold 1/sqrt(HDIM) AND log2(e) into Q so softmax uses raw v_exp_f32
    float scale = (z == 0) ? 0.125f * LOG2E : 1.0f;
    gemm_bf16_body(Xb, Bt, bias, nullptr, out, scale);
}

__global__ __launch_bounds__(256) void out_gemm_kernel(
    const unsigned short* __restrict__ Ob, const unsigned short* __restrict__ Wto,
    const float* __restrict__ bo, float* __restrict__ out)
{
    gemm_bf16_body(Ob, Wto, bo, out, nullptr, 1.0f);
}

// ---------------------------------------------------------------------------
// Flash attention, bf16 MFMA, no-max softmax (scores bounded ~|8*log2e|, exp2
// cannot overflow fp32; masked -> -1e30 -> exp2 flushes to 0 = reference
// semantics). l-sum deferred to a single end reduce. S^T = K.Q^T layout keeps
// 4 consecutive k per lane (uchar4 mask, packed b64 P writes). K/V staged with
// global_load_lds into unpadded [64][64]; Ps XOR-chunk-swizzled (bank-balanced).
// ---------------------------------------------------------------------------
__global__ __launch_bounds__(256) void attn_mfma_kernel(
    const unsigned short* __restrict__ Qb, const unsigned short* __restrict__ Kb,
    const unsigned short* __restrict__ Vt, const unsigned char* __restrict__ mask8,
    unsigned short* __restrict__ Ob)
{
    __shared__ unsigned short Ks[64][64];    // [kseq][d]   8 KB
    __shared__ unsigned short Vs[64][64];    // [d][kseq]   8 KB
    __shared__ unsigned short Ps[4][32][64]; // per-wave [q][kseq], swizzled, 16 KB
    const int tid = threadIdx.x;
    const int lane = tid & 63, wid = tid >> 6;
    const int ln = lane & 15, lg = lane >> 4;
    const int b = blockIdx.z, h = blockIdx.y;
    const int q0 = blockIdx.x * 128 + wid * 32;

    bf16x8 qf[2][2]; // A/B-frag: row q0+mi*16+ln, d = ks*32+lg*8..
#pragma unroll
    for (int mi = 0; mi < 2; mi++)
#pragma unroll
        for (int ks = 0; ks < 2; ks++)
            qf[mi][ks] = *(const bf16x8*)(Qb +
                (size_t)(b * SEQ + q0 + mi * 16 + ln) * EMBED + h * HDIM + ks * 32 + lg * 8);

    f32x4 o[2][4];
#pragma unroll
    for (int mi = 0; mi < 2; mi++)
#pragma unroll
        for (int dj = 0; dj < 4; dj++) o[mi][dj] = (f32x4){0.f, 0.f, 0.f, 0.f};
    float lsum[2] = {0.f, 0.f};

    // staging: 2 gl2lds per buffer (32 rows each), row = 128 B = 8 lanes
    const int srow = tid >> 3;        // 0..31
    const int scol = (tid & 7) * 8;   // 16 B chunks
    const unsigned short* Kp = Kb + (size_t)(b * SEQ + srow) * EMBED + h * HDIM + scol;
    const unsigned short* Vp = Vt + (size_t)((b * HEADS + h) * HDIM + srow) * SEQ + scol;
    unsigned short* lK = &Ks[srow & ~7][0]; // wave-uniform: &Ks[8*wid][0]
    unsigned short* lV = &Vs[srow & ~7][0];

    const unsigned char* mq0 = mask8 + (size_t)b * SEQ * SEQ + (size_t)(q0 + ln) * SEQ;
    const unsigned char* mq1 = mq0 + (size_t)16 * SEQ;

    // loop-invariant swizzled Ps offsets
    int pwr[4], prd[2];
#pragma unroll
    for (int nj = 0; nj < 4; nj++)
        pwr[nj] = (((2 * nj + (lg >> 1)) ^ (ln & 7)) << 3) + ((lg & 1) << 2);
#pragma unroll
    for (int ks = 0; ks < 2; ks++)
        prd[ks] = ((4 * ks + lg) ^ (ln & 7)) << 3;
    unsigned short* ps0 = &Ps[wid][ln][0];
    unsigned short* ps1 = &Ps[wid][16 + ln][0];

    for (int kt = 0; kt < SEQ; kt += 64) {
        __syncthreads();
        gl2lds(Kp + (size_t)kt * EMBED, lK);
        gl2lds(Kp + (size_t)(kt + 32) * EMBED, lK + 32 * 64);
        gl2lds(Vp + kt, lV);
        gl2lds(Vp + (size_t)32 * SEQ + kt, lV + 32 * 64);
        __syncthreads();

        // mask prefetch (independent of MFMAs below)
        uchar4 mv[2][4];
#pragma unroll
        for (int mi = 0; mi < 2; mi++) {
            const unsigned char* mq = (mi ? mq1 : mq0) + kt;
#pragma unroll
            for (int nj = 0; nj < 4; nj++)
                mv[mi][nj] = *(const uchar4*)(mq + nj * 16 + lg * 4);
        }

        // S^T: rows = kseq (nj*16+lg*4+reg), cols = q (mi*16+ln)
        f32x4 S[2][4];
#pragma unroll
        for (int nj = 0; nj < 4; nj++) {
            bf16x8 k0 = *(const bf16x8*)&Ks[nj * 16 + ln][lg * 8];
            bf16x8 k1 = *(const bf16x8*)&Ks[nj * 16 + ln][32 + lg * 8];
#pragma unroll
            for (int mi = 0; mi < 2; mi++) {
                f32x4 t = (f32x4){0.f, 0.f, 0.f, 0.f};
                t = MFMA16(k0, qf[mi][0], t);
                t = MFMA16(k1, qf[mi][1], t);
                S[mi][nj] = t;
            }
        }

        // exp2 + mask + partial row-sum + packed P write (no max, no rescale)
#pragma unroll
        for (int mi = 0; mi < 2; mi++) {
            unsigned short* psb = mi ? ps1 : ps0;
            float rs = 0.f;
#pragma unroll
            for (int nj = 0; nj < 4; nj++) {
                uchar4 m = mv[mi][nj];
                float p0 = m.x ? __builtin_amdgcn_exp2f(S[mi][nj][0]) : 0.f;
                float p1 = m.y ? __builtin_amdgcn_exp2f(S[mi][nj][1]) : 0.f;
                float p2 = m.z ? __builtin_amdgcn_exp2f(S[mi][nj][2]) : 0.f;
                float p3 = m.w ? __builtin_amdgcn_exp2f(S[mi][nj][3]) : 0.f;
                rs += (p0 + p1) + (p2 + p3);
                ushort2 w0 = pk2(p0, p1), w1 = pk2(p2, p3);
                ushort4 pw; pw.x = w0.x; pw.y = w0.y; pw.z = w1.x; pw.w = w1.y;
                *(ushort4*)(psb + pwr[nj]) = pw;
            }
            lsum[mi] += rs;
        }

        // O += P @ V
#pragma unroll
        for (int ks = 0; ks < 2; ks++) {
            bf16x8 p0 = *(const bf16x8*)(ps0 + prd[ks]);
            bf16x8 p1 = *(const bf16x8*)(ps1 + prd[ks]);
#pragma unroll
            for (int dj = 0; dj < 4; dj++) {
                bf16x8 vf = *(const bf16x8*)&Vs[dj * 16 + ln][ks * 32 + lg * 8];
                o[0][dj] = MFMA16(p0, vf, o[0][dj]);
                o[1][dj] = MFMA16(p1, vf, o[1][dj]);
            }
        }
    }

#pragma unroll
    for (int mi = 0; mi < 2; mi++) {
        float l = lsum[mi];
        l += __shfl_xor(l, 16);
        l += __shfl_xor(l, 32);
        float li = 1.0f / l;
        float l0 = __shfl(li, lg * 4 + 0);
        float l1 = __shfl(li, lg * 4 + 1);
        float l2 = __shfl(li, lg * 4 + 2);
        float l3 = __shfl(li, lg * 4 + 3);
#pragma unroll
        for (int dj = 0; dj < 4; dj++) {
            unsigned short* op = Ob + (size_t)(b * SEQ + q0 + mi * 16 + lg * 4) * EMBED
                                    + h * HDIM + dj * 16 + ln;
            ushort2 w0 = pk2(o[mi][dj][0] * l0, o[mi][dj][1] * l1);
            ushort2 w1 = pk2(o[mi][dj][2] * l2, o[mi][dj][3] * l3);
            op[0]         = w0.x;
            op[EMBED]     = w0.y;
            op[2 * EMBED] = w1.x;
            op[3 * EMBED] = w1.y;
        }
    }
}

extern "C" void kernel_launch(void* const* d_in, const int* in_sizes, int n_in,
                              void* d_out, int out_size, void* d_ws, size_t ws_size,
                              hipStream_t stream)
{
    const float* x  = (const float*)d_in[0];
    const int* mask = (const int*)d_in[1];
    const float* Wq = (const float*)d_in[2];
    const float* bq = (const float*)d_in[3];
    const float* Wk = (const float*)d_in[4];
    const float* bk = (const float*)d_in[5];
    const float* Wv = (const float*)d_in[6];
    const float* bv = (const float*)d_in[7];
    const float* Wo = (const float*)d_in[8];
    const float* bo = (const float*)d_in[9];
    float* outp = (float*)d_out;

    // Workspace layout (88 MB):
    //   [0,8)   Wt: 4x bf16 1024x1024 (transposed weights)
    //   [8,24)  mask8
    //   [24,40) Xb (bf16 x) -- aliased by Vt after QKV GEMM consumes Xb
    //   [40,56) Qb  [56,72) Kb  [72,88) Vb -- Vb aliased by Ob after vtrans
    char* ws = (char*)d_ws;
    unsigned short* Wt = (unsigned short*)(ws);
    unsigned char*  m8 = (unsigned char*)(ws + ((size_t)8 << 20));
    unsigned short* Xb = (unsigned short*)(ws + ((size_t)24 << 20));
    unsigned short* Vt = Xb;
    unsigned short* Qb = (unsigned short*)(ws + ((size_t)40 << 20));
    unsigned short* Kb = (unsigned short*)(ws + ((size_t)56 << 20));
    unsigned short* Vb = (unsigned short*)(ws + ((size_t)72 << 20));
    unsigned short* Ob = Vb;

    cvt_x_kernel<<<ROWS * EMBED / 1024, 256, 0, stream>>>(x, Xb);
    wtrans_kernel<<<dim3(32, 32, 4), 256, 0, stream>>>(Wq, Wk, Wv, Wo, Wt);
    cvt_mask_kernel<<<(size_t)BATCH * SEQ * SEQ / 1024, 256, 0, stream>>>(mask, m8);
    qkv_gemm_kernel<<<dim3(EMBED / 128, ROWS / 128, 3), 256, 0, stream>>>(
        Xb, Wt, bq, bk, bv, Qb, Kb, Vb);
    vtrans_kernel<<<dim3(SEQ / 64, HEADS, BATCH), 256, 0, stream>>>(Vb, Vt);
    attn_mfma_kernel<<<dim3(SEQ / 128, HEADS, BATCH), 256, 0, stream>>>(
        Qb, Kb, Vt, m8, Ob);
    out_gemm_kernel<<<dim3(EMBED / 128, ROWS / 128), 256, 0, stream>>>(
        Ob, Wt + (size_t)3 * EMBED * EMBED, bo, outp);
}

// Round 4
// 417.665 us; speedup vs baseline: 7.1779x; 1.0273x over previous
//
#include <hip/hip_runtime.h>
#include <hip/hip_bf16.h>

#define EMBED 1024
#define HEADS 16
#define HDIM 64
#define BATCH 4
#define SEQ 2048
#define ROWS (BATCH * SEQ) /* 8192 */
#define LOG2E 1.4426950408889634f

typedef __attribute__((ext_vector_type(8))) short bf16x8;  // 8 bf16 = 4 VGPRs
typedef __attribute__((ext_vector_type(4))) float f32x4;   // MFMA 16x16 acc

#define MFMA16(a, b, c) __builtin_amdgcn_mfma_f32_16x16x32_bf16(a, b, c, 0, 0, 0)

__device__ __forceinline__ unsigned short f2bf(float f) {
    union { float f; unsigned int u; } x; x.f = f;
    unsigned int r = x.u + 0x7fffu + ((x.u >> 16) & 1u); // RNE
    return (unsigned short)(r >> 16);
}

__device__ __forceinline__ ushort2 pk2(float a, float b) {
    union { __hip_bfloat162 h; ushort2 u; } c;
    c.h = __float22bfloat162_rn(make_float2(a, b)); // packed v_cvt_pk_bf16_f32
    return c.u;
}

// async global->LDS, 16 B per lane; lds dest = wave-uniform base + lane*16
__device__ __forceinline__ void gl2lds(const unsigned short* g, unsigned short* l) {
    __builtin_amdgcn_global_load_lds(
        (const __attribute__((address_space(1))) unsigned int*)g,
        (__attribute__((address_space(3))) unsigned int*)l, 16, 0, 0);
}

// ---------------------------------------------------------------------------
// Prep kernels
// ---------------------------------------------------------------------------
__global__ __launch_bounds__(256) void cvt_x_kernel(
    const float* __restrict__ in, unsigned short* __restrict__ out)
{
    int i = (blockIdx.x * 256 + threadIdx.x) * 4;
    float4 v = *(const float4*)(in + i);
    ushort2 a = pk2(v.x, v.y), b = pk2(v.z, v.w);
    ushort4 o; o.x = a.x; o.y = a.y; o.z = b.x; o.w = b.y;
    *(ushort4*)(out + i) = o;
}

// W (K x N, row-major fp32) -> Wt (N x K, row-major bf16), 4 matrices.
__global__ __launch_bounds__(256) void wtrans_kernel(
    const float* __restrict__ W0, const float* __restrict__ W1,
    const float* __restrict__ W2, const float* __restrict__ W3,
    unsigned short* __restrict__ Wt)
{
    __shared__ float t[32][33];
    const float* W = (blockIdx.z == 0) ? W0 : (blockIdx.z == 1) ? W1
                   : (blockIdx.z == 2) ? W2 : W3;
    unsigned short* o = Wt + (size_t)blockIdx.z * EMBED * EMBED;
    int tx = threadIdx.x & 31, ty = threadIdx.x >> 5;
    int bx = blockIdx.x * 32, by = blockIdx.y * 32;
#pragma unroll
    for (int r = 0; r < 32; r += 8)
        t[ty + r][tx] = W[(size_t)(by + ty + r) * EMBED + bx + tx];
    __syncthreads();
#pragma unroll
    for (int r = 0; r < 32; r += 8)
        o[(size_t)(bx + ty + r) * EMBED + by + tx] = f2bf(t[tx][ty + r]);
}

__global__ __launch_bounds__(256) void cvt_mask_kernel(
    const int* __restrict__ in, unsigned char* __restrict__ out)
{
    int i = (blockIdx.x * 256 + threadIdx.x) * 4;
    int4 v = *(const int4*)(in + i);
    uchar4 o;
    o.x = v.x != 0; o.y = v.y != 0; o.z = v.z != 0; o.w = v.w != 0;
    *(uchar4*)(out + i) = o;
}

// V (row-major [b*SEQ+k][h*64+d] bf16) -> Vt [b][h][d][k] bf16
__global__ __launch_bounds__(256) void vtrans_kernel(
    const unsigned short* __restrict__ Vb, unsigned short* __restrict__ Vt)
{
    __shared__ unsigned short t[64][72];
    int b = blockIdx.z, h = blockIdx.y, k0 = blockIdx.x * 64;
    int r = threadIdx.x >> 2, c = (threadIdx.x & 3) * 16;
    const unsigned short* src = Vb + (size_t)(b * SEQ + k0 + r) * EMBED + h * HDIM + c;
    *(uint4*)&t[r][c]     = *(const uint4*)(src);
    *(uint4*)&t[r][c + 8] = *(const uint4*)(src + 8);
    __syncthreads();
    unsigned short* dst = Vt + (size_t)((b * HEADS + h) * HDIM + r) * SEQ + k0 + c;
    union { unsigned short u[8]; uint4 v; } p0, p1;
#pragma unroll
    for (int i = 0; i < 8; i++) p0.u[i] = t[c + i][r];
#pragma unroll
    for (int i = 0; i < 8; i++) p1.u[i] = t[c + 8 + i][r];
    *(uint4*)dst       = p0.v;
    *(uint4*)(dst + 8) = p1.v;
}

// ---------------------------------------------------------------------------
// bf16 MFMA GEMM, m97-style + XOR-swizzled LDS (swizzle done by permuting the
// gl2lds SOURCE address per lane; DMA dest is fixed base+16*lane).
// 64-B rows (4 chunks): phys_chunk = c ^ (r&3) ^ ((r>>2)&3).
// Fragment read chunk becomes lg ^ (ln&3) ^ (ln>>2): 2-way max per phase.
// ---------------------------------------------------------------------------
__device__ __forceinline__ void gemm_bf16_body(
    const unsigned short* __restrict__ A, const unsigned short* __restrict__ Bt,
    const float* __restrict__ bias,
    float* __restrict__ outF, unsigned short* __restrict__ outB, float scale)
{
    __shared__ unsigned short As[128][32]; // 8 KB
    __shared__ unsigned short Bs[128][32];
    const int tid = threadIdx.x;
    const int lane = tid & 63, wid = tid >> 6;
    const int ln = lane & 15, lg = lane >> 4;
    const int wy = wid >> 1, wx = wid & 1;
    const int m0 = blockIdx.y * 128, n0 = blockIdx.x * 128;
    const int srow = tid >> 2;          // 0..63
    // swizzled source chunk for this lane's DMA slot
    const int scol = (((tid & 3) ^ ((tid >> 2) & 3) ^ ((tid >> 4) & 3)) << 3);
    const unsigned short* Ap = A + (size_t)(m0 + srow) * EMBED + scol;
    const unsigned short* Bp = Bt + (size_t)(n0 + srow) * EMBED + scol;
    unsigned short* lA = &As[srow & ~15][0]; // wave-uniform
    unsigned short* lB = &Bs[srow & ~15][0];
    // swizzled fragment-read column (shorts)
    const int swg = ((lg ^ (ln & 3) ^ (ln >> 2)) << 3);

    f32x4 acc[4][4];
#pragma unroll
    for (int i = 0; i < 4; i++)
#pragma unroll
        for (int j = 0; j < 4; j++) acc[i][j] = (f32x4){0.f, 0.f, 0.f, 0.f};

    for (int k0 = 0; k0 < EMBED; k0 += 32) {
        __syncthreads();
        gl2lds(Ap + k0, lA);
        gl2lds(Ap + (size_t)64 * EMBED + k0, lA + 64 * 32);
        gl2lds(Bp + k0, lB);
        gl2lds(Bp + (size_t)64 * EMBED + k0, lB + 64 * 32);
        __syncthreads();
        bf16x8 af[4], bfr[4];
#pragma unroll
        for (int mi = 0; mi < 4; mi++)
            af[mi] = *(const bf16x8*)&As[wy * 64 + mi * 16 + ln][swg];
#pragma unroll
        for (int nj = 0; nj < 4; nj++)
            bfr[nj] = *(const bf16x8*)&Bs[wx * 64 + nj * 16 + ln][swg];
#pragma unroll
        for (int mi = 0; mi < 4; mi++)
#pragma unroll
            for (int nj = 0; nj < 4; nj++)
                acc[mi][nj] = MFMA16(af[mi], bfr[nj], acc[mi][nj]);
    }

#pragma unroll
    for (int mi = 0; mi < 4; mi++) {
#pragma unroll
        for (int nj = 0; nj < 4; nj++) {
            int row = m0 + wy * 64 + mi * 16 + lg * 4;
            int col = n0 + wx * 64 + nj * 16 + ln;
            float bv = bias[col];
#pragma unroll
            for (int r = 0; r < 4; r++) {
                float v = (acc[mi][nj][r] + bv) * scale;
                if (outF) outF[(size_t)(row + r) * EMBED + col] = v;
                else      outB[(size_t)(row + r) * EMBED + col] = f2bf(v);
            }
        }
    }
}

__global__ __launch_bounds__(256) void qkv_gemm_kernel(
    const unsigned short* __restrict__ Xb, const unsigned short* __restrict__ Wt,
    const float* __restrict__ bq, const float* __restrict__ bk,
    const float* __restrict__ bv,
    unsigned short* __restrict__ Qb, unsigned short* __restrict__ Kb,
    unsigned short* __restrict__ Vb)
{
    int z = blockIdx.z;
    const unsigned short* Bt = Wt + (size_t)z * EMBED * EMBED;
    const float* bias = (z == 0) ? bq : (z == 1) ? bk : bv;
    unsigned short* out = (z == 0) ? Qb : (z == 1) ? Kb : Vb;
    // fold 1/sqrt(HDIM) AND log2(e) into Q so softmax uses raw v_exp_f32
    float scale = (z == 0) ? 0.125f * LOG2E : 1.0f;
    gemm_bf16_body(Xb, Bt, bias, nullptr, out, scale);
}

__global__ __launch_bounds__(256) void out_gemm_kernel(
    const unsigned short* __restrict__ Ob, const unsigned short* __restrict__ Wto,
    const float* __restrict__ bo, float* __restrict__ out)
{
    gemm_bf16_body(Ob, Wto, bo, out, nullptr, 1.0f);
}

// ---------------------------------------------------------------------------
// Flash attention, bf16 MFMA, no-max softmax. K/V tiles [64][64] XOR-chunk
// swizzled via permuted DMA sources (phys_chunk = c ^ (row&7)); fragment
// reads use chunk lg^(ln&7) -> 2-way max per phase (free). Row-sum l computed
// by an extra MFMA against a constant all-ones B fragment: l arrives in
// C-layout (row = lg*4+r), exactly matching O rows -> no end shuffles.
// ---------------------------------------------------------------------------
__global__ __launch_bounds__(256) void attn_mfma_kernel(
    const unsigned short* __restrict__ Qb, const unsigned short* __restrict__ Kb,
    const unsigned short* __restrict__ Vt, const unsigned char* __restrict__ mask8,
    unsigned short* __restrict__ Ob)
{
    __shared__ unsigned short Ks[64][64];    // [kseq][d]   8 KB (swizzled)
    __shared__ unsigned short Vs[64][64];    // [d][kseq]   8 KB (swizzled)
    __shared__ unsigned short Ps[4][32][64]; // per-wave [q][kseq], swizzled, 16 KB
    const int tid = threadIdx.x;
    const int lane = tid & 63, wid = tid >> 6;
    const int ln = lane & 15, lg = lane >> 4;
    const int b = blockIdx.z, h = blockIdx.y;
    const int q0 = blockIdx.x * 128 + wid * 32;

    bf16x8 qf[2][2]; // A/B-frag: row q0+mi*16+ln, d = ks*32+lg*8..
#pragma unroll
    for (int mi = 0; mi < 2; mi++)
#pragma unroll
        for (int ks = 0; ks < 2; ks++)
            qf[mi][ks] = *(const bf16x8*)(Qb +
                (size_t)(b * SEQ + q0 + mi * 16 + ln) * EMBED + h * HDIM + ks * 32 + lg * 8);

    bf16x8 ones;
#pragma unroll
    for (int i = 0; i < 8; i++) ones[i] = (short)0x3F80; // bf16 1.0

    f32x4 o[2][4];
#pragma unroll
    for (int mi = 0; mi < 2; mi++)
#pragma unroll
        for (int dj = 0; dj < 4; dj++) o[mi][dj] = (f32x4){0.f, 0.f, 0.f, 0.f};
    f32x4 lacc[2] = {(f32x4){0.f, 0.f, 0.f, 0.f}, (f32x4){0.f, 0.f, 0.f, 0.f}};

    // staging: srow = tid>>3 (0..31), swizzled source chunk = (tid&7)^((tid>>3)&7)
    const int srow = tid >> 3;
    const int scolKV = (((tid & 7) ^ ((tid >> 3) & 7)) << 3);
    const unsigned short* Kp = Kb + (size_t)(b * SEQ + srow) * EMBED + h * HDIM + scolKV;
    const unsigned short* Vp = Vt + (size_t)((b * HEADS + h) * HDIM + srow) * SEQ + scolKV;
    unsigned short* lK = &Ks[srow & ~7][0]; // wave-uniform
    unsigned short* lV = &Vs[srow & ~7][0];

    const unsigned char* mq0 = mask8 + (size_t)b * SEQ * SEQ + (size_t)(q0 + ln) * SEQ;
    const unsigned char* mq1 = mq0 + (size_t)16 * SEQ;

    // swizzled fragment-read column for Ks/Vs: chunk lg^(ln&7); k1/ks flip bit
    const int swk = ((lg ^ (ln & 7)) << 3);

    // Ps swizzle offsets (verified self-consistent, 2-way max)
    int pwr[4], prd[2];
#pragma unroll
    for (int nj = 0; nj < 4; nj++)
        pwr[nj] = (((2 * nj + (lg >> 1)) ^ (ln & 7)) << 3) + ((lg & 1) << 2);
#pragma unroll
    for (int ks = 0; ks < 2; ks++)
        prd[ks] = ((4 * ks + lg) ^ (ln & 7)) << 3;
    unsigned short* ps0 = &Ps[wid][ln][0];
    unsigned short* ps1 = &Ps[wid][16 + ln][0];

    for (int kt = 0; kt < SEQ; kt += 64) {
        // mask loads first: independent of LDS, overlap the barriers
        uchar4 mv[2][4];
#pragma unroll
        for (int mi = 0; mi < 2; mi++) {
            const unsigned char* mq = (mi ? mq1 : mq0) + kt;
#pragma unroll
            for (int nj = 0; nj < 4; nj++)
                mv[mi][nj] = *(const uchar4*)(mq + nj * 16 + lg * 4);
        }

        __syncthreads();
        gl2lds(Kp + (size_t)kt * EMBED, lK);
        gl2lds(Kp + (size_t)(kt + 32) * EMBED, lK + 32 * 64);
        gl2lds(Vp + kt, lV);
        gl2lds(Vp + (size_t)32 * SEQ + kt, lV + 32 * 64);
        __syncthreads();

        // S^T: rows = kseq (nj*16+lg*4+reg), cols = q (mi*16+ln)
        f32x4 S[2][4];
#pragma unroll
        for (int nj = 0; nj < 4; nj++) {
            bf16x8 k0 = *(const bf16x8*)&Ks[nj * 16 + ln][swk];
            bf16x8 k1 = *(const bf16x8*)&Ks[nj * 16 + ln][swk ^ 32];
#pragma unroll
            for (int mi = 0; mi < 2; mi++) {
                f32x4 t = (f32x4){0.f, 0.f, 0.f, 0.f};
                t = MFMA16(k0, qf[mi][0], t);
                t = MFMA16(k1, qf[mi][1], t);
                S[mi][nj] = t;
            }
        }

        // exp2 + mask + packed P write (no max, no rescale, no VALU row-sum)
#pragma unroll
        for (int mi = 0; mi < 2; mi++) {
            unsigned short* psb = mi ? ps1 : ps0;
#pragma unroll
            for (int nj = 0; nj < 4; nj++) {
                uchar4 m = mv[mi][nj];
                float p0 = m.x ? __builtin_amdgcn_exp2f(S[mi][nj][0]) : 0.f;
                float p1 = m.y ? __builtin_amdgcn_exp2f(S[mi][nj][1]) : 0.f;
                float p2 = m.z ? __builtin_amdgcn_exp2f(S[mi][nj][2]) : 0.f;
                float p3 = m.w ? __builtin_amdgcn_exp2f(S[mi][nj][3]) : 0.f;
                ushort2 w0 = pk2(p0, p1), w1 = pk2(p2, p3);
                ushort4 pw; pw.x = w0.x; pw.y = w0.y; pw.z = w1.x; pw.w = w1.y;
                *(ushort4*)(psb + pwr[nj]) = pw;
            }
        }

        // O += P @ V ; l += P @ ones (l lands in C-layout matching O rows)
#pragma unroll
        for (int ks = 0; ks < 2; ks++) {
            bf16x8 p0 = *(const bf16x8*)(ps0 + prd[ks]);
            bf16x8 p1 = *(const bf16x8*)(ps1 + prd[ks]);
            lacc[0] = MFMA16(p0, ones, lacc[0]);
            lacc[1] = MFMA16(p1, ones, lacc[1]);
#pragma unroll
            for (int dj = 0; dj < 4; dj++) {
                bf16x8 vf = *(const bf16x8*)&Vs[dj * 16 + ln][swk ^ (ks << 5)];
                o[0][dj] = MFMA16(p0, vf, o[0][dj]);
                o[1][dj] = MFMA16(p1, vf, o[1][dj]);
            }
        }
    }

#pragma unroll
    for (int mi = 0; mi < 2; mi++) {
        float l0 = 1.0f / lacc[mi][0];
        float l1 = 1.0f / lacc[mi][1];
        float l2 = 1.0f / lacc[mi][2];
        float l3 = 1.0f / lacc[mi][3];
#pragma unroll
        for (int dj = 0; dj < 4; dj++) {
            unsigned short* op = Ob + (size_t)(b * SEQ + q0 + mi * 16 + lg * 4) * EMBED
                                    + h * HDIM + dj * 16 + ln;
            ushort2 w0 = pk2(o[mi][dj][0] * l0, o[mi][dj][1] * l1);
            ushort2 w1 = pk2(o[mi][dj][2] * l2, o[mi][dj][3] * l3);
            op[0]         = w0.x;
            op[EMBED]     = w0.y;
            op[2 * EMBED] = w1.x;
            op[3 * EMBED] = w1.y;
        }
    }
}

extern "C" void kernel_launch(void* const* d_in, const int* in_sizes, int n_in,
                              void* d_out, int out_size, void* d_ws, size_t ws_size,
                              hipStream_t stream)
{
    const float* x  = (const float*)d_in[0];
    const int* mask = (const int*)d_in[1];
    const float* Wq = (const float*)d_in[2];
    const float* bq = (const float*)d_in[3];
    const float* Wk = (const float*)d_in[4];
    const float* bk = (const float*)d_in[5];
    const float* Wv = (const float*)d_in[6];
    const float* bv = (const float*)d_in[7];
    const float* Wo = (const float*)d_in[8];
    const float* bo = (const float*)d_in[9];
    float* outp = (float*)d_out;

    // Workspace layout (88 MB):
    //   [0,8)   Wt: 4x bf16 1024x1024 (transposed weights)
    //   [8,24)  mask8
    //   [24,40) Xb (bf16 x) -- aliased by Vt after QKV GEMM consumes Xb
    //   [40,56) Qb  [56,72) Kb  [72,88) Vb -- Vb aliased by Ob after vtrans
    char* ws = (char*)d_ws;
    unsigned short* Wt = (unsigned short*)(ws);
    unsigned char*  m8 = (unsigned char*)(ws + ((size_t)8 << 20));
    unsigned short* Xb = (unsigned short*)(ws + ((size_t)24 << 20));
    unsigned short* Vt = Xb;
    unsigned short* Qb = (unsigned short*)(ws + ((size_t)40 << 20));
    unsigned short* Kb = (unsigned short*)(ws + ((size_t)56 << 20));
    unsigned short* Vb = (unsigned short*)(ws + ((size_t)72 << 20));
    unsigned short* Ob = Vb;

    cvt_x_kernel<<<ROWS * EMBED / 1024, 256, 0, stream>>>(x, Xb);
    wtrans_kernel<<<dim3(32, 32, 4), 256, 0, stream>>>(Wq, Wk, Wv, Wo, Wt);
    cvt_mask_kernel<<<(size_t)BATCH * SEQ * SEQ / 1024, 256, 0, stream>>>(mask, m8);
    qkv_gemm_kernel<<<dim3(EMBED / 128, ROWS / 128, 3), 256, 0, stream>>>(
        Xb, Wt, bq, bk, bv, Qb, Kb, Vb);
    vtrans_kernel<<<dim3(SEQ / 64, HEADS, BATCH), 256, 0, stream>>>(Vb, Vt);
    attn_mfma_kernel<<<dim3(SEQ / 128, HEADS, BATCH), 256, 0, stream>>>(
        Qb, Kb, Vt, m8, Ob);
    out_gemm_kernel<<<dim3(EMBED / 128, ROWS / 128), 256, 0, stream>>>(
        Ob, Wt + (size_t)3 * EMBED * EMBED, bo, outp);
}